// Round 6
// baseline (356.968 us; speedup 1.0000x reference)
//
#include <hip/hip_runtime.h>

#define B 32
#define N 512
#define P 8
#define H 300
#define EPSN 1e-12f
#define NT 32
#define NB (N / NT)       // 16

typedef _Float16 f16x8 __attribute__((ext_vector_type(8)));
typedef float f32x4 __attribute__((ext_vector_type(4)));

// ---------- prep_w: W (P,H,H fp32) -> fragment-ordered fp16 (runs once, ~10 us) ----------
// fb = (p*10+ht)*20 + kt; elem = fb*512 + l*8 + j; h = ht*32+(l>>4)*8+j, k = kt*16+(l&15)
__global__ __launch_bounds__(256)
void nsm_prep_w(const float* __restrict__ W, _Float16* __restrict__ wfrag)
{
    const int gid  = blockIdx.x * 256 + threadIdx.x;
    const int fb   = gid >> 6;            // 0..1599 (400 blocks * 4 waves)
    const int lane = gid & 63;
    const int p  = fb / 200;
    const int rm = fb % 200;
    const int ht = rm / 20;
    const int kt = rm % 20;
    const int k  = kt * 16 + (lane & 15);
    const int h0 = ht * 32 + (lane >> 4) * 8;

    f16x8 v;
    #pragma unroll
    for (int j = 0; j < 8; ++j) {
        int h = h0 + j;
        float wv = (h < H && k < H) ? W[((size_t)p * H + h) * H + k] : 0.f;
        v[j] = (_Float16)wv;
    }
    *(f16x8*)(wfrag + (size_t)fb * 512 + (size_t)lane * 8) = v;
}

// ---------- fused main: stage A in LDS (double-buffered), barrier-1-per-p, MFMA ----------
// Block: 32 n-rows, all 320 k. Wave w: k in [80w,80w+80). LDS A layout: unit
// u = ht*2+nt (20 units x 512 halfs), lane-swizzled: off = u*512 + (lw*8 ^ ((lw>>4&3)<<3)).
__global__ __launch_bounds__(256, 2)
void nsm_fused(const float* __restrict__ node_attr,
               const float* __restrict__ instruction,
               const float* __restrict__ nps,
               const _Float16* __restrict__ wfrag,
               const float* __restrict__ w_state,
               float* __restrict__ pscore)
{
    __shared__ _Float16 sA[2][20 * 512];   // 2 x 20 KB
    __shared__ float sI[320];

    const int t  = threadIdx.x;
    const int nb = blockIdx.x;
    const int b  = blockIdx.y;
    const int w  = t >> 6, l = t & 63;
    const int r  = t >> 3, oc = t & 7;     // staging role: row 0..31, oct 0..7

    for (int i = t; i < 320; i += 256)
        sI[i] = (i < H) ? instruction[b * H + i] : 0.f;

    const float* srcA = node_attr + ((size_t)(b * N + nb * NT + r) * P) * H;
    const int szl = (l * 8) ^ (((l >> 4) & 3) << 3);     // swizzled read off (halfs)
    const _Float16* Wb = wfrag + (size_t)(w * 5) * 512 + (size_t)l * 8;

    float4 va[5], vb[5];

    auto loadA = [&](int pp) {
        const float* src = srcA + (size_t)pp * H;
        #pragma unroll
        for (int i = 0; i < 5; ++i) {
            int o = oc + i * 8, h0 = o * 8;
            va[i] = make_float4(0.f, 0.f, 0.f, 0.f);
            vb[i] = make_float4(0.f, 0.f, 0.f, 0.f);
            if (o < 37) {
                va[i] = *(const float4*)(src + h0);
                vb[i] = *(const float4*)(src + h0 + 4);
            } else if (o == 37) {          // h 296..299 valid only
                va[i] = *(const float4*)(src + h0);
            }
        }
    };
    auto convWrite = [&](int buf) {
        _Float16* dst = sA[buf];
        #pragma unroll
        for (int i = 0; i < 5; ++i) {
            int o = oc + i * 8, h0 = o * 8;
            float4 sa = *(const float4*)&sI[h0];     // sI[>=300] = 0 -> pads zero
            float4 sb = *(const float4*)&sI[h0 + 4];
            f16x8 v8;
            v8[0] = (_Float16)(va[i].x * sa.x); v8[1] = (_Float16)(va[i].y * sa.y);
            v8[2] = (_Float16)(va[i].z * sa.z); v8[3] = (_Float16)(va[i].w * sa.w);
            v8[4] = (_Float16)(vb[i].x * sb.x); v8[5] = (_Float16)(vb[i].y * sb.y);
            v8[6] = (_Float16)(vb[i].z * sb.z); v8[7] = (_Float16)(vb[i].w * sb.w);
            int u  = (o >> 2) * 2 + (r >> 4);
            int lw = ((o & 3) << 4) | (r & 15);
            int off = u * 512 + ((lw * 8) ^ ((o & 3) << 3));
            *(f16x8*)&dst[off] = v8;
        }
    };

    loadA(0);
    __syncthreads();          // sI visible
    convWrite(0);
    __syncthreads();          // sA[0] ready

    f32x4 S1[2][5], S2[2][5];
    #pragma unroll
    for (int nt = 0; nt < 2; ++nt)
        #pragma unroll
        for (int kt = 0; kt < 5; ++kt) {
            S1[nt][kt] = (f32x4){0.f, 0.f, 0.f, 0.f};
            S2[nt][kt] = (f32x4){0.f, 0.f, 0.f, 0.f};
        }

    for (int p = 0; p < P; ++p) {
        if (p < 7) loadA(p + 1);           // issue early: HBM latency hides under MFMA

        const _Float16* sbuf = sA[p & 1];
        const _Float16* Wp = Wb + (size_t)(p * 200) * 512;

        f32x4 acc[2][5];
        #pragma unroll
        for (int nt = 0; nt < 2; ++nt)
            #pragma unroll
            for (int kt = 0; kt < 5; ++kt)
                acc[nt][kt] = (f32x4){0.f, 0.f, 0.f, 0.f};

        f16x8 ab[2][2], wf[2][5];
        ab[0][0] = *(const f16x8*)&sbuf[0 * 512 + szl];
        ab[0][1] = *(const f16x8*)&sbuf[1 * 512 + szl];
        #pragma unroll
        for (int kt = 0; kt < 5; ++kt)
            wf[0][kt] = *(const f16x8*)(Wp + (size_t)kt * 512);

        #pragma unroll
        for (int ht = 0; ht < 10; ++ht) {
            const int cur = ht & 1, nxt = cur ^ 1;
            if (ht < 9) {
                ab[nxt][0] = *(const f16x8*)&sbuf[((ht + 1) * 2 + 0) * 512 + szl];
                ab[nxt][1] = *(const f16x8*)&sbuf[((ht + 1) * 2 + 1) * 512 + szl];
                #pragma unroll
                for (int kt = 0; kt < 5; ++kt)
                    wf[nxt][kt] = *(const f16x8*)(Wp + (size_t)((ht + 1) * 20 + kt) * 512);
            }
            #pragma unroll
            for (int kt = 0; kt < 5; ++kt) {
                acc[0][kt] = __builtin_amdgcn_mfma_f32_16x16x32_f16(ab[cur][0], wf[cur][kt], acc[0][kt], 0, 0, 0);
                acc[1][kt] = __builtin_amdgcn_mfma_f32_16x16x32_f16(ab[cur][1], wf[cur][kt], acc[1][kt], 0, 0, 0);
            }
        }

        if (p < 7) convWrite((p + 1) & 1); // write-late into the other buffer

        const float sim = nps[b * P + p];
        #pragma unroll
        for (int nt = 0; nt < 2; ++nt)
            #pragma unroll
            for (int kt = 0; kt < 5; ++kt) {
                f32x4 z = acc[nt][kt] * sim;
                S1[nt][kt] += z;
                S2[nt][kt] += z * z;
            }
        __syncthreads();                   // buf (p+1) ready / reads of buf p done
    }

    // epilogue: normalize over P, elu, dot w_state, reduce k-16-group, per-wave partial
    // C/D: col(k)=l&15, row=(l>>4)*4+j
    #pragma unroll
    for (int nt = 0; nt < 2; ++nt) {
        #pragma unroll
        for (int j = 0; j < 4; ++j) {
            float part = 0.f;
            #pragma unroll
            for (int kt = 0; kt < 5; ++kt) {
                int k = w * 80 + kt * 16 + (l & 15);
                if (k < H) {
                    float s1 = S1[nt][kt][j];
                    float s2 = S2[nt][kt][j];
                    float denom = fmaxf(sqrtf(s2), EPSN);
                    float v = s1 / denom;
                    float e = v > 0.f ? v : expm1f(v);
                    part += e * w_state[k];
                }
            }
            part += __shfl_xor(part, 1, 16);
            part += __shfl_xor(part, 2, 16);
            part += __shfl_xor(part, 4, 16);
            part += __shfl_xor(part, 8, 16);
            if ((l & 15) == 0) {
                int row = nt * 16 + (l >> 4) * 4 + j;
                pscore[(size_t)w * (B * N) + (size_t)b * N + nb * NT + row] = part;
            }
        }
    }
}

// ---------- softmax: sum 4 wave-partials, masked softmax over N ----------
__global__ __launch_bounds__(256)
void nsm_softmax_kernel(const float* __restrict__ pscore,
                        const float* __restrict__ mask,
                        float* __restrict__ out)
{
    __shared__ float redm[4];
    __shared__ float reds[4];
    const int b = blockIdx.x;
    const int t = threadIdx.x;

    float v0 = mask[b * N + t];
    float v1 = mask[b * N + 256 + t];
    #pragma unroll
    for (int w = 0; w < 4; ++w) {
        v0 += pscore[(size_t)w * (B * N) + b * N + t];
        v1 += pscore[(size_t)w * (B * N) + b * N + 256 + t];
    }

    float m = fmaxf(v0, v1);
    m = fmaxf(m, __shfl_xor(m, 1, 64));
    m = fmaxf(m, __shfl_xor(m, 2, 64));
    m = fmaxf(m, __shfl_xor(m, 4, 64));
    m = fmaxf(m, __shfl_xor(m, 8, 64));
    m = fmaxf(m, __shfl_xor(m, 16, 64));
    m = fmaxf(m, __shfl_xor(m, 32, 64));
    const int wave = t >> 6;
    const int lane = t & 63;
    if (lane == 0) redm[wave] = m;
    __syncthreads();
    m = fmaxf(fmaxf(redm[0], redm[1]), fmaxf(redm[2], redm[3]));

    float e0 = expf(v0 - m);
    float e1 = expf(v1 - m);
    float s = e0 + e1;
    s += __shfl_xor(s, 1, 64);
    s += __shfl_xor(s, 2, 64);
    s += __shfl_xor(s, 4, 64);
    s += __shfl_xor(s, 8, 64);
    s += __shfl_xor(s, 16, 64);
    s += __shfl_xor(s, 32, 64);
    if (lane == 0) reds[wave] = s;
    __syncthreads();
    s = reds[0] + reds[1] + reds[2] + reds[3];

    out[b * N + t]       = e0 / s;
    out[b * N + 256 + t] = e1 / s;
}

extern "C" void kernel_launch(void* const* d_in, const int* in_sizes, int n_in,
                              void* d_out, int out_size, void* d_ws, size_t ws_size,
                              hipStream_t stream)
{
    const float* node_attr   = (const float*)d_in[0];
    const float* instruction = (const float*)d_in[2];
    const float* nps         = (const float*)d_in[5];
    const float* node_mask   = (const float*)d_in[6];
    const float* W_node      = (const float*)d_in[7];
    const float* w_state     = (const float*)d_in[8];
    float* out = (float*)d_out;

    _Float16* wfrag  = (_Float16*)d_ws;            // 1600*512 halfs = 1.64 MB
    float*    pscore = (float*)(wfrag + 1600 * 512);  // 4*B*N floats = 256 KB

    nsm_prep_w<<<dim3(400), 256, 0, stream>>>(W_node, wfrag);
    nsm_fused<<<dim3(NB, B), 256, 0, stream>>>(node_attr, instruction, nps,
                                               wfrag, w_state, pscore);
    nsm_softmax_kernel<<<dim3(B), 256, 0, stream>>>(pscore, node_mask, out);
}